// Round 7
// baseline (742.111 us; speedup 1.0000x reference)
//
#include <hip/hip_runtime.h>
#include <math.h>

#define NXY  1024
#define NZ   24
#define ROI2 512      // 2*ROISize
#define LO_  256      // Nxy/2 - ROISize
#define EXT  64       // NxyExt
#define IMGW 896      // Nxy - 2*EXT
#define ITN  2
#define SNR_ 200.0f
#define BKG  110.0f
#define RANK1 524287u
#define RANK2 524288u
#define NACC 4
// LDS swizzle for the wave-FFT exchanges: injects bits [7:4] into [3:0].
// All read/write patterns (stride-64 reads, 16*lane+m and q+256p+16m writes)
// land at 4 lanes per bank-pair = the wave64 minimum (conflict-free).
#define LSWZ(i) ((i) ^ (((i) >> 4) & 15))

typedef float2 cf;

__device__ __forceinline__ cf cadd(cf a, cf b) { return make_float2(a.x + b.x, a.y + b.y); }
__device__ __forceinline__ cf csub(cf a, cf b) { return make_float2(a.x - b.x, a.y - b.y); }
__device__ __forceinline__ cf cmul(cf a, cf b) { return make_float2(a.x * b.x - a.y * b.y, a.x * b.y + a.y * b.x); }

template <int SIGN>
__device__ __forceinline__ cf wc(float cr, float ci) { return make_float2(cr, SIGN < 0 ? ci : -ci); }

template <int SIGN>
__device__ __forceinline__ void dft4r(cf& a0, cf& a1, cf& a2, cf& a3) {
  cf b0 = cadd(a0, a2), b1 = csub(a0, a2);
  cf b2 = cadd(a1, a3), b3 = csub(a1, a3);
  cf jb3 = (SIGN < 0) ? make_float2(b3.y, -b3.x) : make_float2(-b3.y, b3.x);
  a0 = cadd(b0, b2); a2 = csub(b0, b2);
  a1 = cadd(b1, jb3); a3 = csub(b1, jb3);
}

// In-register DFT-16, natural order in/out (two radix-4 Stockham stages, const twiddles).
template <int SIGN>
__device__ __forceinline__ void dft16r(cf* x) {
  const cf W1 = wc<SIGN>(0.92387953251f, -0.38268343236f);
  const cf W2 = wc<SIGN>(0.70710678119f, -0.70710678119f);
  const cf W3 = wc<SIGN>(0.38268343236f, -0.92387953251f);
  const cf W4 = wc<SIGN>(0.f, -1.f);
  const cf W6 = wc<SIGN>(-0.70710678119f, -0.70710678119f);
  const cf W9 = wc<SIGN>(-0.92387953251f, 0.38268343236f);
  cf t[16];
#pragma unroll
  for (int p = 0; p < 4; ++p) {
    cf a0 = x[p], a1 = x[p + 4], a2 = x[p + 8], a3 = x[p + 12];
    dft4r<SIGN>(a0, a1, a2, a3);
    if (p == 1) { a1 = cmul(a1, W1); a2 = cmul(a2, W2); a3 = cmul(a3, W3); }
    else if (p == 2) { a1 = cmul(a1, W2); a2 = cmul(a2, W4); a3 = cmul(a3, W6); }
    else if (p == 3) { a1 = cmul(a1, W3); a2 = cmul(a2, W6); a3 = cmul(a3, W9); }
    t[4 * p] = a0; t[4 * p + 1] = a1; t[4 * p + 2] = a2; t[4 * p + 3] = a3;
  }
#pragma unroll
  for (int q = 0; q < 4; ++q) {
    cf a0 = t[q], a1 = t[q + 4], a2 = t[q + 8], a3 = t[q + 12];
    dft4r<SIGN>(a0, a1, a2, a3);
    x[q] = a0; x[q + 4] = a1; x[q + 8] = a2; x[q + 12] = a3;
  }
}

// w[m] = w1^m via log-depth product tree (m = 0..15)
__device__ __forceinline__ void twpow(cf* w, cf w1) {
  w[0] = make_float2(1.f, 0.f);
  w[1] = w1;
  w[2] = cmul(w1, w1);   w[3] = cmul(w[2], w1);
  w[4] = cmul(w[2], w[2]); w[5] = cmul(w[3], w[2]);
  w[6] = cmul(w[3], w[3]); w[7] = cmul(w[4], w[3]);
  w[8] = cmul(w[4], w[4]); w[9] = cmul(w[5], w[4]);
  w[10] = cmul(w[5], w[5]); w[11] = cmul(w[6], w[5]);
  w[12] = cmul(w[6], w[6]); w[13] = cmul(w[7], w[6]);
  w[14] = cmul(w[7], w[7]); w[15] = cmul(w[8], w[7]);
}

// 1024-pt FFT per WAVE: regs r[m] = x[lane + 64m] in/out (natural order), L = 8KB
// wave-private LDS. Radices 16,16,4; 2 in-place LDS exchanges; no barriers (wave lockstep).
template <int SIGN>
__device__ void fft1024_wave(cf* r, cf* L, int lane) {
  const float TH = (SIGN < 0) ? -6.28318530717958647692f : 6.28318530717958647692f;
  cf w[16];
  float sv, cv;
  // stage 0: radix-16, s=1, p=lane; twiddle W^(lane*m)
  dft16r<SIGN>(r);
  sincosf(TH * (float)lane * (1.0f / 1024.0f), &sv, &cv);
  twpow(w, make_float2(cv, sv));
#pragma unroll
  for (int m = 1; m < 16; ++m) r[m] = cmul(r[m], w[m]);
#pragma unroll
  for (int m = 0; m < 16; ++m) L[LSWZ(16 * lane + m)] = r[m];
#pragma unroll
  for (int m = 0; m < 16; ++m) r[m] = L[LSWZ(lane + 64 * m)];
  // stage 1: radix-16, s=16, q=lane&15, p=lane>>4; twiddle W^(16*p*m)
  dft16r<SIGN>(r);
  int p1 = lane >> 4, q1 = lane & 15;
  sincosf(TH * (float)p1 * (1.0f / 64.0f), &sv, &cv);
  twpow(w, make_float2(cv, sv));
#pragma unroll
  for (int m = 1; m < 16; ++m) r[m] = cmul(r[m], w[m]);
#pragma unroll
  for (int m = 0; m < 16; ++m) L[LSWZ(q1 + 256 * p1 + 16 * m)] = r[m];
#pragma unroll
  for (int j = 0; j < 16; ++j) r[j] = L[LSWZ(lane + 64 * j)];
  // stage 2: radix-4, s=256, in registers, no twiddle
#pragma unroll
  for (int a = 0; a < 4; ++a) dft4r<SIGN>(r[a], r[a + 4], r[a + 8], r[a + 12]);
  // r[j] = X[lane + 64j]
}

// ---------------- setup kernels ----------------
__global__ void ksum_kernel(const float* __restrict__ a, float* __restrict__ out) {
  __shared__ float s[256];
  int tid = threadIdx.x;
  float acc = 0.f;
  for (int i = blockIdx.x * 256 + tid; i < NXY * NXY; i += gridDim.x * 256) acc += a[i];
  s[tid] = acc;
  __syncthreads();
  for (int o = 128; o > 0; o >>= 1) {
    if (tid < o) s[tid] += s[tid + o];
    __syncthreads();
  }
  if (tid == 0) atomicAdd(out, s[0]);
}

__global__ void imgexp_kernel(const float* __restrict__ im, float* __restrict__ out) {
  int idx = blockIdx.x * 256 + threadIdx.x;
  int r = idx >> 10, c = idx & 1023;
  float v = 0.f;
  if (r >= EXT && r < NXY - EXT && c >= EXT && c < NXY - EXT) {
    float t = im[(size_t)(r - EXT) * IMGW + (c - EXT)] - BKG;
    v = t > 0.f ? t : 0.f;
  }
  out[idx] = v;
}

// KH_T[kx][ky] = Hermitian part of K, transposed. Re(ifft2(F*K)) == ifft2(F*K_H).
__global__ void buildkh_kernel(const float* __restrict__ kre, const float* __restrict__ kim,
                               cf* __restrict__ kt) {
  int idx = blockIdx.x * 256 + threadIdx.x;
  if (idx >= 513 * 1024) return;
  int ky = idx & 1023, kx = idx >> 10;
  int ny = (1024 - ky) & 1023, nx = (1024 - kx) & 1023;
  float ar = kre[(size_t)ky * NXY + kx], ai = kim[(size_t)ky * NXY + kx];
  float br = kre[(size_t)ny * NXY + nx], bi = kim[(size_t)ny * NXY + nx];
  kt[idx] = make_float2(0.5f * (ar + br), 0.5f * (ai - bi));
}

// transpose [R][C] -> [C][R], batched over blockIdx.z; grid (C/32, R/32, z)
__global__ void transpose_kernel(const cf* __restrict__ in, cf* __restrict__ out, int R, int C) {
  __shared__ cf tile[32][33];
  size_t zoff = (size_t)blockIdx.z * R * C;
  const cf* src = in + zoff;
  cf* dst = out + zoff;
  int bc = blockIdx.x * 32, br = blockIdx.y * 32;
  int tx = threadIdx.x, ty = threadIdx.y;
#pragma unroll
  for (int j = 0; j < 32; j += 8) tile[ty + j][tx] = src[(size_t)(br + ty + j) * C + bc + tx];
  __syncthreads();
#pragma unroll
  for (int j = 0; j < 32; j += 8) dst[(size_t)(bc + ty + j) * R + br + tx] = tile[tx][ty + j];
}

// ---------------- FFT pipeline kernels (wave-per-FFT) ----------------
// Row rFFT of TWO real 512-rows (ROI, support [256,768)). grid = (64, zn).
// Wave w handles pair b = bx*4+w. out: [z][512][512] cf (col 0 packs F[0],F[512]).
__global__ __launch_bounds__(256) void pass1_kernel(const float* __restrict__ in, cf* __restrict__ out) {
  __shared__ cf Lb[4][1024];
  int tid = threadIdx.x, wid = tid >> 6, lane = tid & 63;
  cf* L = Lb[wid];
  int b = blockIdx.x * 4 + wid, z = blockIdx.y;
  const float* r0 = in + ((size_t)z * 512 + 2 * b) * 512;
  const float* r1 = r0 + 512;
  cf r[16];
#pragma unroll
  for (int m = 0; m < 16; ++m) r[m] = make_float2(0.f, 0.f);
#pragma unroll
  for (int m = 4; m < 12; ++m) {
    int idx = lane + 64 * m - 256;
    r[m] = make_float2(r0[idx], r1[idx]);
  }
  fft1024_wave<-1>(r, L, lane);
#pragma unroll
  for (int j = 0; j < 16; ++j) L[LSWZ(lane + 64 * j)] = r[j];
  cf* o0 = out + ((size_t)z * 512 + 2 * b) * 512;
  cf* o1 = o0 + 512;
#pragma unroll
  for (int j = 0; j < 8; ++j) {
    int k = lane + 64 * j;
    int nk = k ? (1024 - k) : 512;
    cf c = L[LSWZ(k)], d = L[LSWZ(nk)];
    if (k == 0) {
      o0[0] = make_float2(c.x, d.x);
      o1[0] = make_float2(c.y, d.y);
    } else {
      o0[k] = make_float2(0.5f * (c.x + d.x), 0.5f * (c.y - d.y));
      o1[k] = make_float2(0.5f * (c.y + d.y), 0.5f * (d.x - c.x));
    }
  }
}

// Back-projection row rFFT with ratio fused. grid = (128). rows (2b,2b+1); out [1024][512].
__global__ __launch_bounds__(256) void pass1b_kernel(const float* __restrict__ iexp,
                                                     const float* __restrict__ iest,
                                                     const float* __restrict__ tos,
                                                     cf* __restrict__ out) {
  __shared__ cf Lb[4][1024];
  int tid = threadIdx.x, wid = tid >> 6, lane = tid & 63;
  cf* L = Lb[wid];
  int b = blockIdx.x * 4 + wid;
  float t = tos[0];
  int r0 = 2 * b, r1 = 2 * b + 1;
  bool in0 = (r0 >= EXT && r0 < NXY - EXT);
  bool in1 = (r1 >= EXT && r1 < NXY - EXT);
  cf r[16];
#pragma unroll
  for (int m = 0; m < 16; ++m) {
    int k = lane + 64 * m;
    bool kin = (k >= EXT && k < NXY - EXT);
    float v0 = (in0 && kin) ? iexp[(size_t)r0 * NXY + k] / (iest[(size_t)r0 * NXY + k] + t) : 1.0f;
    float v1 = (in1 && kin) ? iexp[(size_t)r1 * NXY + k] / (iest[(size_t)r1 * NXY + k] + t) : 1.0f;
    r[m] = make_float2(v0, v1);
  }
  fft1024_wave<-1>(r, L, lane);
#pragma unroll
  for (int j = 0; j < 16; ++j) L[LSWZ(lane + 64 * j)] = r[j];
  cf* o0 = out + (size_t)r0 * 512;
  cf* o1 = out + (size_t)r1 * 512;
#pragma unroll
  for (int j = 0; j < 8; ++j) {
    int k = lane + 64 * j;
    int nk = k ? (1024 - k) : 512;
    cf c = L[LSWZ(k)], d = L[LSWZ(nk)];
    if (k == 0) {
      o0[0] = make_float2(c.x, d.x);
      o1[0] = make_float2(c.y, d.y);
    } else {
      o0[k] = make_float2(0.5f * (c.x + d.x), 0.5f * (c.y - d.y));
      o1[k] = make_float2(0.5f * (c.y + d.y), 0.5f * (d.x - c.x));
    }
  }
}

// Column FFT * K_H (conj opt) * column IFFT, one wave per column. grid = (128, zn).
// Wave kc==0 handles BOTH packed real columns (kx=0,512) via two-real split.
// HALFIN=1: input support [256,768), inLen=512 (forward). Else inLen=1024.
template <int HALFIN>
__global__ __launch_bounds__(256) void pass2_kernel(const cf* __restrict__ in,
                                                    const cf* __restrict__ kt, cf* __restrict__ out,
                                                    int conjK) {
  __shared__ cf Lb[4][1024];
  int tid = threadIdx.x, wid = tid >> 6, lane = tid & 63;
  cf* L = Lb[wid];
  int kc = blockIdx.x * 4 + wid, z = blockIdx.y;
  cf kva[16];
#pragma unroll
  for (int j = 0; j < 16; ++j) {
    kva[j] = kt[(size_t)kc * NXY + lane + 64 * j];
    if (conjK) kva[j].y = -kva[j].y;
  }
  const int inLen = HALFIN ? 512 : 1024;
  const cf* src = in + ((size_t)z * 512 + kc) * inLen;
  cf r[16];
  if (HALFIN) {
#pragma unroll
    for (int m = 0; m < 16; ++m) r[m] = make_float2(0.f, 0.f);
#pragma unroll
    for (int m = 4; m < 12; ++m) r[m] = src[lane + 64 * m - 256];
  } else {
#pragma unroll
    for (int m = 0; m < 16; ++m) r[m] = src[lane + 64 * m];
  }
  fft1024_wave<-1>(r, L, lane);
  if (kc == 0) {
    // packed pair: split into col-0 (a) and col-512 (b) spectra, K-mul each, recombine
#pragma unroll
    for (int j = 0; j < 16; ++j) L[LSWZ(lane + 64 * j)] = r[j];
#pragma unroll
    for (int j = 0; j < 16; ++j) {
      int k = lane + 64 * j;
      int nk = (1024 - k) & 1023;
      cf c = L[LSWZ(k)], d = L[LSWZ(nk)];
      cf Fa = make_float2(0.5f * (c.x + d.x), 0.5f * (c.y - d.y));
      cf Fb = make_float2(0.5f * (c.y + d.y), 0.5f * (d.x - c.x));
      cf kb = kt[(size_t)512 * NXY + k];
      if (conjK) kb.y = -kb.y;
      cf Ga = cmul(Fa, kva[j]);
      cf Gb = cmul(Fb, kb);
      r[j] = make_float2(Ga.x - Gb.y, Ga.y + Gb.x);
    }
  } else {
#pragma unroll
    for (int j = 0; j < 16; ++j) r[j] = cmul(r[j], kva[j]);
  }
  fft1024_wave<1>(r, L, lane);
  cf* dst = out + ((size_t)z * 512 + kc) * NXY;
#pragma unroll
  for (int j = 0; j < 16; ++j) dst[lane + 64 * j] = r[j];
}

// Row irFFT (pair) + scale + ReLU into partial plane a. grid = (128, NACC).
// in: [z][1024][512] cf (col 0 packed). Wave owns rows (2b, 2b+1), z-loop stride NACC.
__global__ __launch_bounds__(256) void pass3_fwd_kernel(const cf* __restrict__ in,
                                                        float* __restrict__ partials,
                                                        const float* __restrict__ ksump, int zn,
                                                        int accum) {
  __shared__ cf Lb[4][1024];
  int tid = threadIdx.x, wid = tid >> 6, lane = tid & 63;
  cf* L = Lb[wid];
  int b = blockIdx.x * 4 + wid, a = blockIdx.y;
  float scale = 1.0f / (1048576.0f * ksump[0]);
  int r0 = 2 * b, r1 = 2 * b + 1;
  cf acc[16];
#pragma unroll
  for (int j = 0; j < 16; ++j) acc[j] = make_float2(0.f, 0.f);
  cf r[16];
  for (int z = a; z < zn; z += NACC) {
    const cf* s0 = in + ((size_t)z * NXY + r0) * 512;
    const cf* s1 = s0 + 512;
#pragma unroll
    for (int j = 0; j < 8; ++j) {
      int k = lane + 64 * j;
      cf u0 = s0[k], u1 = s1[k];
      if (k == 0) {
        L[LSWZ(0)]   = make_float2(u0.x, u1.x);
        L[LSWZ(512)] = make_float2(u0.y, u1.y);
      } else {
        L[LSWZ(k)]        = make_float2(u0.x - u1.y, u0.y + u1.x);
        L[LSWZ(1024 - k)] = make_float2(u0.x + u1.y, u1.x - u0.y);
      }
    }
#pragma unroll
    for (int m = 0; m < 16; ++m) r[m] = L[LSWZ(lane + 64 * m)];
    fft1024_wave<1>(r, L, lane);
#pragma unroll
    for (int j = 0; j < 16; ++j) {
      float v0 = r[j].x * scale, v1 = r[j].y * scale;
      acc[j].x += v0 > 0.f ? v0 : 0.f;
      acc[j].y += v1 > 0.f ? v1 : 0.f;
    }
  }
  float* d0 = partials + ((size_t)a * NXY + r0) * NXY;
  float* d1 = d0 + NXY;
  if (accum) {
#pragma unroll
    for (int j = 0; j < 16; ++j) { d0[lane + 64 * j] += acc[j].x; d1[lane + 64 * j] += acc[j].y; }
  } else {
#pragma unroll
    for (int j = 0; j < 16; ++j) { d0[lane + 64 * j] = acc[j].x; d1[lane + 64 * j] = acc[j].y; }
  }
}

// fold partials -> IEst; re-init median state
__global__ void fold_kernel(const float* __restrict__ partials, float* __restrict__ iest,
                            unsigned* __restrict__ st) {
  int i = blockIdx.x * 256 + threadIdx.x;
  float s = 0.f;
#pragma unroll
  for (int a = 0; a < NACC; ++a) s += partials[(size_t)a * NXY * NXY + i];
  iest[i] = s;
  if (i == 0) { st[0] = 0u; st[1] = 0u; st[2] = RANK1; st[3] = RANK2; }
}

// Back-projection row irFFT (pair) + ReLU + multiply into obj. grid = (64).
__global__ __launch_bounds__(256) void pass3_back_kernel(const cf* __restrict__ in, float* __restrict__ obj,
                                                         const float* __restrict__ ksump) {
  __shared__ cf Lb[4][1024];
  int tid = threadIdx.x, wid = tid >> 6, lane = tid & 63;
  cf* L = Lb[wid];
  int b = blockIdx.x * 4 + wid;
  float scale = 1.0f / (1048576.0f * ksump[0]);
  int r0 = LO_ + 2 * b, r1 = r0 + 1;
  const cf* s0 = in + (size_t)r0 * 512;
  const cf* s1 = in + (size_t)r1 * 512;
#pragma unroll
  for (int j = 0; j < 8; ++j) {
    int k = lane + 64 * j;
    cf u0 = s0[k], u1 = s1[k];
    if (k == 0) {
      L[LSWZ(0)]   = make_float2(u0.x, u1.x);
      L[LSWZ(512)] = make_float2(u0.y, u1.y);
    } else {
      L[LSWZ(k)]        = make_float2(u0.x - u1.y, u0.y + u1.x);
      L[LSWZ(1024 - k)] = make_float2(u0.x + u1.y, u1.x - u0.y);
    }
  }
  cf r[16];
#pragma unroll
  for (int m = 0; m < 16; ++m) r[m] = L[LSWZ(lane + 64 * m)];
  fft1024_wave<1>(r, L, lane);
  // keep ROI columns [256,768) -> j = 4..11; store (relu0, relu1) per column in L[0..511]
#pragma unroll
  for (int j = 4; j < 12; ++j) {
    int c = lane + 64 * j - 256;
    float v0 = r[j].x * scale, v1 = r[j].y * scale;
    L[c] = make_float2(v0 > 0.f ? v0 : 0.f, v1 > 0.f ? v1 : 0.f);
  }
  int rp0 = 2 * b, rp1 = 2 * b + 1;
  for (int idx = lane; idx < NZ * 512; idx += 64) {
    int z = idx >> 9, c = idx & 511;
    cf br = L[c];
    obj[((size_t)z * ROI2 + rp0) * ROI2 + c] *= br.x;
    obj[((size_t)z * ROI2 + rp1) * ROI2 + c] *= br.y;
  }
}

// ---------------- median (exact, 3-round radix-select; pick fused via last-block) ----------------
// hist region layout: [0..2*nb) bins, [4096] finish counter. 256 blocks.
__global__ void medhist_kernel(const float* __restrict__ v, unsigned* __restrict__ st,
                               unsigned* __restrict__ hist, int shift, unsigned maskHigh, int nb,
                               int finalRound, float* __restrict__ tos) {
  extern __shared__ unsigned h[];
  __shared__ unsigned ps[256];
  __shared__ int lastFlag;
  int tid = threadIdx.x;
  for (int k = tid; k < 2 * nb; k += 256) h[k] = 0u;
  __syncthreads();
  unsigned p1 = st[0], p2 = st[1];
  unsigned bm = (unsigned)(nb - 1);
  for (int i = blockIdx.x * 256 + tid; i < NXY * NXY; i += gridDim.x * 256) {
    unsigned u = __float_as_uint(v[i]);
    unsigned b = (u >> shift) & bm;
    if ((u & maskHigh) == (p1 & maskHigh)) atomicAdd(&h[b], 1u);
    if ((u & maskHigh) == (p2 & maskHigh)) atomicAdd(&h[nb + b], 1u);
  }
  __syncthreads();
  for (int k = tid; k < 2 * nb; k += 256) atomicAdd(&hist[k], h[k]);
  __syncthreads();
  if (tid == 0) {
    __threadfence();
    lastFlag = (atomicAdd(&hist[4096], 1u) == (unsigned)(gridDim.x - 1)) ? 1 : 0;
  }
  __syncthreads();
  if (!lastFlag) return;
  // last block: pick both pivots from the completed global histogram
  int per = nb >> 8;
  for (int which = 0; which < 2; ++which) {
    unsigned loc[8];
    unsigned my = 0;
    for (int i = 0; i < per; ++i) { loc[i] = atomicAdd(&hist[which * nb + tid * per + i], 0u); my += loc[i]; }
    ps[tid] = my;
    __syncthreads();
    for (int off = 1; off < 256; off <<= 1) {
      unsigned vv = (tid >= off) ? ps[tid - off] : 0u;
      __syncthreads();
      ps[tid] += vv;
      __syncthreads();
    }
    unsigned pre = ps[tid] - my;
    unsigned rr = st[2 + which];
    if (rr >= pre && rr < pre + my) {
      unsigned cum = pre;
      for (int i = 0; i < per; ++i) {
        if (rr < cum + loc[i]) {
          st[which] |= (unsigned)(tid * per + i) << shift;
          st[2 + which] = rr - cum;
          break;
        }
        cum += loc[i];
      }
    }
    __syncthreads();
  }
  if (finalRound && tid == 0) {
    float m = 0.5f * (__uint_as_float(st[0]) + __uint_as_float(st[1]));
    tos[0] = m / SNR_;
  }
}

// ---------------- orchestration ----------------
extern "C" void kernel_launch(void* const* d_in, const int* in_sizes, int n_in,
                              void* d_out, int out_size, void* d_ws, size_t ws_size,
                              hipStream_t stream) {
  const float* imstack  = (const float*)d_in[0];
  const float* init_vol = (const float*)d_in[1];
  const float* conv_re  = (const float*)d_in[2];
  const float* conv_im  = (const float*)d_in[3];
  float* obj = (float*)d_out;

  char* w = (char*)d_ws;
  size_t off = 0;
  auto alloc = [&](size_t bytes) -> void* {
    void* p = (void*)(w + off);
    off += (bytes + 255) & ~(size_t)255;
    return p;
  };

  const size_t PLANE = (size_t)NXY * NXY;
  const size_t HPLANE = (size_t)512 * NXY;
  cf* KT         = (cf*)alloc((size_t)513 * NXY * sizeof(cf)); // 4.2 MB
  float* IExp    = (float*)alloc(PLANE * 4);
  float* IEst    = (float*)alloc(PLANE * 4);
  float* Partial = (float*)alloc((size_t)NACC * PLANE * 4);    // 16 MB
  float* Ksum    = (float*)alloc(256);
  unsigned* St   = (unsigned*)alloc(256);
  unsigned* Hist = (unsigned*)alloc(3 * 4160 * 4);             // 3 rounds: 4096 bins + counter
  size_t fixedEnd = off;

  int ZC = 2;
  const int zcs[7] = {24, 12, 8, 6, 4, 3, 2};
  for (int i = 0; i < 7; ++i) {
    size_t need = fixedEnd + (size_t)zcs[i] * 2ull * HPLANE * sizeof(cf) + 4096;
    if (need <= ws_size) { ZC = zcs[i]; break; }
  }
  cf* bufC = (cf*)alloc((size_t)ZC * HPLANE * sizeof(cf));
  cf* bufD = (cf*)alloc((size_t)ZC * HPLANE * sizeof(cf));
  float* Tos = Ksum + 1;

  hipMemcpyAsync(obj, init_vol, (size_t)NZ * ROI2 * ROI2 * 4, hipMemcpyDeviceToDevice, stream);
  hipMemsetAsync(Ksum, 0, 8, stream);
  ksum_kernel<<<256, 256, 0, stream>>>(conv_re, Ksum);
  imgexp_kernel<<<4096, 256, 0, stream>>>(imstack, IExp);
  buildkh_kernel<<<2052, 256, 0, stream>>>(conv_re, conv_im, KT);

  const int shifts[3] = {21, 10, 0};
  const int nbs[3]    = {2048, 2048, 1024};
  const unsigned masks[3] = {0u, 0xFFE00000u, 0xFFFFFC00u};

  for (int it = 0; it < ITN; ++it) {
    // forward projection in z-chunks (f32 half-spectrum, wave-FFT pipeline)
    for (int z0 = 0; z0 < NZ; z0 += ZC) {
      int zn = (NZ - z0 < ZC) ? (NZ - z0) : ZC;
      pass1_kernel<<<dim3(64, zn), 256, 0, stream>>>(obj + (size_t)z0 * ROI2 * ROI2, bufC);
      transpose_kernel<<<dim3(16, 16, zn), dim3(32, 8), 0, stream>>>(bufC, bufD, 512, 512);
      pass2_kernel<1><<<dim3(128, zn), 256, 0, stream>>>(bufD, KT, bufC, 0);
      transpose_kernel<<<dim3(32, 16, zn), dim3(32, 8), 0, stream>>>(bufC, bufD, 512, 1024);
      pass3_fwd_kernel<<<dim3(128, NACC), 256, 0, stream>>>(bufD, Partial, Ksum, zn, z0 > 0 ? 1 : 0);
    }
    fold_kernel<<<4096, 256, 0, stream>>>(Partial, IEst, St);
    // exact median of IEst (pick fused into hist via last-block pattern)
    hipMemsetAsync(Hist, 0, 3 * 4160 * 4, stream);
    for (int round = 0; round < 3; ++round) {
      medhist_kernel<<<256, 256, 2 * nbs[round] * 4, stream>>>(IEst, St, Hist + round * 4160,
                                                               shifts[round], masks[round], nbs[round],
                                                               round == 2 ? 1 : 0, Tos);
    }
    // back projection (ratio fused; conj(K_H); full-input path)
    pass1b_kernel<<<128, 256, 0, stream>>>(IExp, IEst, Tos, bufC);                   // [1024][512]
    transpose_kernel<<<dim3(16, 32, 1), dim3(32, 8), 0, stream>>>(bufC, bufD, 1024, 512);
    pass2_kernel<0><<<dim3(128, 1), 256, 0, stream>>>(bufD, KT, bufC, 1);            // [512][1024]
    transpose_kernel<<<dim3(32, 16, 1), dim3(32, 8), 0, stream>>>(bufC, bufD, 512, 1024);
    pass3_back_kernel<<<64, 256, 0, stream>>>(bufD, obj, Ksum);
  }
}

// Round 8
// 590.539 us; speedup vs baseline: 1.2567x; 1.2567x over previous
//
#include <hip/hip_runtime.h>
#include <math.h>

#define NXY  1024
#define NZ   24
#define ROI2 512      // 2*ROISize
#define LO_  256      // Nxy/2 - ROISize
#define EXT  64       // NxyExt
#define IMGW 896      // Nxy - 2*EXT
#define ITN  2
#define SNR_ 200.0f
#define BKG  110.0f
#define RANK1 524287u
#define RANK2 524288u
#define NACC 4
// LDS swizzle for wave-FFT exchanges (conflict-free at wave64 minimum).
#define LSWZ(i) ((i) ^ (((i) >> 4) & 15))

typedef float2 cf;

__device__ __forceinline__ cf cadd(cf a, cf b) { return make_float2(a.x + b.x, a.y + b.y); }
__device__ __forceinline__ cf csub(cf a, cf b) { return make_float2(a.x - b.x, a.y - b.y); }
__device__ __forceinline__ cf cmul(cf a, cf b) { return make_float2(a.x * b.x - a.y * b.y, a.x * b.y + a.y * b.x); }

template <int SIGN>
__device__ __forceinline__ cf wc(float cr, float ci) { return make_float2(cr, SIGN < 0 ? ci : -ci); }

template <int SIGN>
__device__ __forceinline__ void dft4r(cf& a0, cf& a1, cf& a2, cf& a3) {
  cf b0 = cadd(a0, a2), b1 = csub(a0, a2);
  cf b2 = cadd(a1, a3), b3 = csub(a1, a3);
  cf jb3 = (SIGN < 0) ? make_float2(b3.y, -b3.x) : make_float2(-b3.y, b3.x);
  a0 = cadd(b0, b2); a2 = csub(b0, b2);
  a1 = cadd(b1, jb3); a3 = csub(b1, jb3);
}

// In-register DFT-16, natural order in/out.
template <int SIGN>
__device__ __forceinline__ void dft16r(cf* x) {
  const cf W1 = wc<SIGN>(0.92387953251f, -0.38268343236f);
  const cf W2 = wc<SIGN>(0.70710678119f, -0.70710678119f);
  const cf W3 = wc<SIGN>(0.38268343236f, -0.92387953251f);
  const cf W4 = wc<SIGN>(0.f, -1.f);
  const cf W6 = wc<SIGN>(-0.70710678119f, -0.70710678119f);
  const cf W9 = wc<SIGN>(-0.92387953251f, 0.38268343236f);
  cf t[16];
#pragma unroll
  for (int p = 0; p < 4; ++p) {
    cf a0 = x[p], a1 = x[p + 4], a2 = x[p + 8], a3 = x[p + 12];
    dft4r<SIGN>(a0, a1, a2, a3);
    if (p == 1) { a1 = cmul(a1, W1); a2 = cmul(a2, W2); a3 = cmul(a3, W3); }
    else if (p == 2) { a1 = cmul(a1, W2); a2 = cmul(a2, W4); a3 = cmul(a3, W6); }
    else if (p == 3) { a1 = cmul(a1, W3); a2 = cmul(a2, W6); a3 = cmul(a3, W9); }
    t[4 * p] = a0; t[4 * p + 1] = a1; t[4 * p + 2] = a2; t[4 * p + 3] = a3;
  }
#pragma unroll
  for (int q = 0; q < 4; ++q) {
    cf a0 = t[q], a1 = t[q + 4], a2 = t[q + 8], a3 = t[q + 12];
    dft4r<SIGN>(a0, a1, a2, a3);
    x[q] = a0; x[q + 4] = a1; x[q + 8] = a2; x[q + 12] = a3;
  }
}

// w[m] = w1^m, m = 0..15
__device__ __forceinline__ void twpow(cf* w, cf w1) {
  w[0] = make_float2(1.f, 0.f);
  w[1] = w1;
  w[2] = cmul(w1, w1);   w[3] = cmul(w[2], w1);
  w[4] = cmul(w[2], w[2]); w[5] = cmul(w[3], w[2]);
  w[6] = cmul(w[3], w[3]); w[7] = cmul(w[4], w[3]);
  w[8] = cmul(w[4], w[4]); w[9] = cmul(w[5], w[4]);
  w[10] = cmul(w[5], w[5]); w[11] = cmul(w[6], w[5]);
  w[12] = cmul(w[6], w[6]); w[13] = cmul(w[7], w[6]);
  w[14] = cmul(w[7], w[7]); w[15] = cmul(w[8], w[7]);
}

// 1024-pt FFT per WAVE: r[m] = x[lane + 64m] in/out, L = wave-private 8KB LDS.
template <int SIGN>
__device__ void fft1024_wave(cf* r, cf* L, int lane) {
  const float TH = (SIGN < 0) ? -6.28318530717958647692f : 6.28318530717958647692f;
  cf w[16];
  float sv, cv;
  dft16r<SIGN>(r);
  sincosf(TH * (float)lane * (1.0f / 1024.0f), &sv, &cv);
  twpow(w, make_float2(cv, sv));
#pragma unroll
  for (int m = 1; m < 16; ++m) r[m] = cmul(r[m], w[m]);
#pragma unroll
  for (int m = 0; m < 16; ++m) L[LSWZ(16 * lane + m)] = r[m];
#pragma unroll
  for (int m = 0; m < 16; ++m) r[m] = L[LSWZ(lane + 64 * m)];
  dft16r<SIGN>(r);
  int p1 = lane >> 4, q1 = lane & 15;
  sincosf(TH * (float)p1 * (1.0f / 64.0f), &sv, &cv);
  twpow(w, make_float2(cv, sv));
#pragma unroll
  for (int m = 1; m < 16; ++m) r[m] = cmul(r[m], w[m]);
#pragma unroll
  for (int m = 0; m < 16; ++m) L[LSWZ(q1 + 256 * p1 + 16 * m)] = r[m];
#pragma unroll
  for (int j = 0; j < 16; ++j) r[j] = L[LSWZ(lane + 64 * j)];
#pragma unroll
  for (int a = 0; a < 4; ++a) dft4r<SIGN>(r[a], r[a + 4], r[a + 8], r[a + 12]);
}

// ---------------- setup kernels ----------------
__global__ void ksum_kernel(const float* __restrict__ a, float* __restrict__ out) {
  __shared__ float s[256];
  int tid = threadIdx.x;
  float acc = 0.f;
  for (int i = blockIdx.x * 256 + tid; i < NXY * NXY; i += gridDim.x * 256) acc += a[i];
  s[tid] = acc;
  __syncthreads();
  for (int o = 128; o > 0; o >>= 1) {
    if (tid < o) s[tid] += s[tid + o];
    __syncthreads();
  }
  if (tid == 0) atomicAdd(out, s[0]);
}

__global__ void imgexp_kernel(const float* __restrict__ im, float* __restrict__ out) {
  int idx = blockIdx.x * 256 + threadIdx.x;
  int r = idx >> 10, c = idx & 1023;
  float v = 0.f;
  if (r >= EXT && r < NXY - EXT && c >= EXT && c < NXY - EXT) {
    float t = im[(size_t)(r - EXT) * IMGW + (c - EXT)] - BKG;
    v = t > 0.f ? t : 0.f;
  }
  out[idx] = v;
}

// KH_T[kx][ky] = Hermitian part of K, transposed. Re(ifft2(F*K)) == ifft2(F*K_H).
__global__ void buildkh_kernel(const float* __restrict__ kre, const float* __restrict__ kim,
                               cf* __restrict__ kt) {
  int idx = blockIdx.x * 256 + threadIdx.x;
  if (idx >= 513 * 1024) return;
  int ky = idx & 1023, kx = idx >> 10;
  int ny = (1024 - ky) & 1023, nx = (1024 - kx) & 1023;
  float ar = kre[(size_t)ky * NXY + kx], ai = kim[(size_t)ky * NXY + kx];
  float br = kre[(size_t)ny * NXY + nx], bi = kim[(size_t)ny * NXY + nx];
  kt[idx] = make_float2(0.5f * (ar + br), 0.5f * (ai - bi));
}

// ---------------- FFT pipeline (wave-per-FFT, transposed I/O via LDS tiles) ----------------
// S1 = 512*512 (KXR slice, cf), S2 = 512*1024 (KXY slice, cf)
#define S1 262144
#define S2 524288

// Row rFFT of ROI rows, TWO real rows per wave; block = 4 waves = 8 rows.
// Writes TRANSPOSED: out[z][kx 512][r 512], 64B contiguous per kx. grid = (64, zn).
__global__ __launch_bounds__(256) void pass1_kernel(const float* __restrict__ in, cf* __restrict__ out) {
  __shared__ cf B[4096];                       // 32KB: 4 wave regions / 8x512 tile
  int tid = threadIdx.x, wid = tid >> 6, lane = tid & 63;
  cf* L = B + wid * 1024;
  int B0 = blockIdx.x, z = blockIdx.y;
  int p = B0 * 4 + wid;                        // row pair 0..255
  const float* r0 = in + ((size_t)z * 512 + 2 * p) * 512;
  const float* r1 = r0 + 512;
  cf r[16];
#pragma unroll
  for (int m = 0; m < 16; ++m) r[m] = make_float2(0.f, 0.f);
#pragma unroll
  for (int m = 4; m < 12; ++m) {
    int idx = lane + 64 * m - 256;
    r[m] = make_float2(r0[idx], r1[idx]);
  }
  fft1024_wave<-1>(r, L, lane);
#pragma unroll
  for (int j = 0; j < 16; ++j) L[LSWZ(lane + 64 * j)] = r[j];
  // Hermitian split into regs (k = lane + 64j, j<8)
  cf o0v[8], o1v[8];
#pragma unroll
  for (int j = 0; j < 8; ++j) {
    int k = lane + 64 * j;
    int nk = k ? (1024 - k) : 512;
    cf c = L[LSWZ(k)], d = L[LSWZ(nk)];
    if (k == 0) { o0v[j] = make_float2(c.x, d.x); o1v[j] = make_float2(c.y, d.y); }
    else {
      o0v[j] = make_float2(0.5f * (c.x + d.x), 0.5f * (c.y - d.y));
      o1v[j] = make_float2(0.5f * (c.y + d.y), 0.5f * (d.x - c.x));
    }
  }
  // tile store (wave-local region = rows 2*wid, 2*wid+1 of the 8x512 tile)
#pragma unroll
  for (int j = 0; j < 8; ++j) {
    int k = lane + 64 * j;
    L[k] = o0v[j];
    L[512 + k] = o1v[j];
  }
  __syncthreads();
  // transposed write: thread t owns kx = t, t+256; 8 consecutive r per kx (64B)
#pragma unroll
  for (int h = 0; h < 2; ++h) {
    int kx = tid + 256 * h;
    float4* dst = (float4*)(out + (size_t)z * S1 + (size_t)kx * 512 + 8 * B0);
#pragma unroll
    for (int ii = 0; ii < 4; ++ii) {
      cf a = B[(2 * ii) * 512 + kx], b = B[(2 * ii + 1) * 512 + kx];
      dst[ii] = make_float4(a.x, a.y, b.x, b.y);
    }
  }
}

// Back-projection row rFFT with ratio fused; block = 4 waves = 8 rows y.
// Writes TRANSPOSED: out[kx 512][y 1024]. grid = (128).
__global__ __launch_bounds__(256) void pass1b_kernel(const float* __restrict__ iexp,
                                                     const float* __restrict__ iest,
                                                     const float* __restrict__ tos,
                                                     cf* __restrict__ out) {
  __shared__ cf B[4096];
  int tid = threadIdx.x, wid = tid >> 6, lane = tid & 63;
  cf* L = B + wid * 1024;
  int B0 = blockIdx.x;
  int b = B0 * 4 + wid;
  float t = tos[0];
  int r0 = 2 * b, r1 = 2 * b + 1;
  bool in0 = (r0 >= EXT && r0 < NXY - EXT);
  bool in1 = (r1 >= EXT && r1 < NXY - EXT);
  cf r[16];
#pragma unroll
  for (int m = 0; m < 16; ++m) {
    int k = lane + 64 * m;
    bool kin = (k >= EXT && k < NXY - EXT);
    float v0 = (in0 && kin) ? iexp[(size_t)r0 * NXY + k] / (iest[(size_t)r0 * NXY + k] + t) : 1.0f;
    float v1 = (in1 && kin) ? iexp[(size_t)r1 * NXY + k] / (iest[(size_t)r1 * NXY + k] + t) : 1.0f;
    r[m] = make_float2(v0, v1);
  }
  fft1024_wave<-1>(r, L, lane);
#pragma unroll
  for (int j = 0; j < 16; ++j) L[LSWZ(lane + 64 * j)] = r[j];
  cf o0v[8], o1v[8];
#pragma unroll
  for (int j = 0; j < 8; ++j) {
    int k = lane + 64 * j;
    int nk = k ? (1024 - k) : 512;
    cf c = L[LSWZ(k)], d = L[LSWZ(nk)];
    if (k == 0) { o0v[j] = make_float2(c.x, d.x); o1v[j] = make_float2(c.y, d.y); }
    else {
      o0v[j] = make_float2(0.5f * (c.x + d.x), 0.5f * (c.y - d.y));
      o1v[j] = make_float2(0.5f * (c.y + d.y), 0.5f * (d.x - c.x));
    }
  }
#pragma unroll
  for (int j = 0; j < 8; ++j) {
    int k = lane + 64 * j;
    L[k] = o0v[j];
    L[512 + k] = o1v[j];
  }
  __syncthreads();
#pragma unroll
  for (int h = 0; h < 2; ++h) {
    int kx = tid + 256 * h;
    float4* dst = (float4*)(out + (size_t)kx * NXY + 8 * B0);
#pragma unroll
    for (int ii = 0; ii < 4; ++ii) {
      cf a = B[(2 * ii) * 512 + kx], b = B[(2 * ii + 1) * 512 + kx];
      dst[ii] = make_float4(a.x, a.y, b.x, b.y);
    }
  }
}

// Column FFT * K_H (conj opt) * column IFFT, one wave per kx column. grid = (128, zn).
// HALFIN=1: in[z][kx][r 512] (support -> y [256,768)); else in[kx][y 1024].
// out: [z][kx 512][y 1024]. Wave kc==0 handles both packed real columns.
template <int HALFIN>
__global__ __launch_bounds__(256) void pass2_kernel(const cf* __restrict__ in,
                                                    const cf* __restrict__ kt, cf* __restrict__ out,
                                                    int conjK) {
  __shared__ cf Lb[4][1024];
  int tid = threadIdx.x, wid = tid >> 6, lane = tid & 63;
  cf* L = Lb[wid];
  int kc = blockIdx.x * 4 + wid, z = blockIdx.y;
  cf kva[16];
#pragma unroll
  for (int j = 0; j < 16; ++j) {
    kva[j] = kt[(size_t)kc * NXY + lane + 64 * j];
    if (conjK) kva[j].y = -kva[j].y;
  }
  const int inLen = HALFIN ? 512 : 1024;
  const cf* src = in + ((size_t)z * 512 + kc) * inLen;
  cf r[16];
  if (HALFIN) {
#pragma unroll
    for (int m = 0; m < 16; ++m) r[m] = make_float2(0.f, 0.f);
#pragma unroll
    for (int m = 4; m < 12; ++m) r[m] = src[lane + 64 * m - 256];
  } else {
#pragma unroll
    for (int m = 0; m < 16; ++m) r[m] = src[lane + 64 * m];
  }
  fft1024_wave<-1>(r, L, lane);
  if (kc == 0) {
#pragma unroll
    for (int j = 0; j < 16; ++j) L[LSWZ(lane + 64 * j)] = r[j];
#pragma unroll
    for (int j = 0; j < 16; ++j) {
      int k = lane + 64 * j;
      int nk = (1024 - k) & 1023;
      cf c = L[LSWZ(k)], d = L[LSWZ(nk)];
      cf Fa = make_float2(0.5f * (c.x + d.x), 0.5f * (c.y - d.y));
      cf Fb = make_float2(0.5f * (c.y + d.y), 0.5f * (d.x - c.x));
      cf kb = kt[(size_t)512 * NXY + k];
      if (conjK) kb.y = -kb.y;
      cf Ga = cmul(Fa, kva[j]);
      cf Gb = cmul(Fb, kb);
      r[j] = make_float2(Ga.x - Gb.y, Ga.y + Gb.x);
    }
  } else {
#pragma unroll
    for (int j = 0; j < 16; ++j) r[j] = cmul(r[j], kva[j]);
  }
  fft1024_wave<1>(r, L, lane);
  cf* dst = out + ((size_t)z * 512 + kc) * NXY;
#pragma unroll
  for (int j = 0; j < 16; ++j) dst[lane + 64 * j] = r[j];
}

// Row irFFT + scale + ReLU into partial plane. Gathers 8-row x 512-kx tile from
// [z][kx][y] layout (64B/ kx). Block = 4 waves = 8 rows y. grid = (128, NACC).
__global__ __launch_bounds__(256) void pass3_fwd_kernel(const cf* __restrict__ in,
                                                        float* __restrict__ partials,
                                                        const float* __restrict__ ksump, int zn,
                                                        int accum) {
  __shared__ cf B[4096];
  int tid = threadIdx.x, wid = tid >> 6, lane = tid & 63;
  cf* L = B + wid * 1024;
  int B0 = blockIdx.x, a = blockIdx.y;
  int y0 = 8 * B0;
  float scale = 1.0f / (1048576.0f * ksump[0]);
  cf acc[16];
#pragma unroll
  for (int j = 0; j < 16; ++j) acc[j] = make_float2(0.f, 0.f);
  cf r[16];
  for (int z = a; z < zn; z += NACC) {
    if (z != a) __syncthreads();
    // gather tile: thread t owns kx = t, t+256 (8 consecutive y = 4 float4)
#pragma unroll
    for (int h = 0; h < 2; ++h) {
      int kx = tid + 256 * h;
      const float4* src = (const float4*)(in + (size_t)z * S2 + (size_t)kx * NXY + y0);
      float4 g0 = src[0], g1 = src[1], g2 = src[2], g3 = src[3];
      B[0 * 512 + kx] = make_float2(g0.x, g0.y);
      B[1 * 512 + kx] = make_float2(g0.z, g0.w);
      B[2 * 512 + kx] = make_float2(g1.x, g1.y);
      B[3 * 512 + kx] = make_float2(g1.z, g1.w);
      B[4 * 512 + kx] = make_float2(g2.x, g2.y);
      B[5 * 512 + kx] = make_float2(g2.z, g2.w);
      B[6 * 512 + kx] = make_float2(g3.x, g3.y);
      B[7 * 512 + kx] = make_float2(g3.z, g3.w);
    }
    __syncthreads();
    // wave-local: rows 2*wid, 2*wid+1 live in this wave's region (L[0..511], L[512..1023])
    cf u0[8], u1[8];
#pragma unroll
    for (int j = 0; j < 8; ++j) {
      int k = lane + 64 * j;
      u0[j] = L[k];
      u1[j] = L[512 + k];
    }
#pragma unroll
    for (int j = 0; j < 8; ++j) {
      int k = lane + 64 * j;
      if (k == 0) {
        L[LSWZ(0)]   = make_float2(u0[j].x, u1[j].x);
        L[LSWZ(512)] = make_float2(u0[j].y, u1[j].y);
      } else {
        L[LSWZ(k)]        = make_float2(u0[j].x - u1[j].y, u0[j].y + u1[j].x);
        L[LSWZ(1024 - k)] = make_float2(u0[j].x + u1[j].y, u1[j].x - u0[j].y);
      }
    }
#pragma unroll
    for (int m = 0; m < 16; ++m) r[m] = L[LSWZ(lane + 64 * m)];
    fft1024_wave<1>(r, L, lane);
#pragma unroll
    for (int j = 0; j < 16; ++j) {
      float v0 = r[j].x * scale, v1 = r[j].y * scale;
      acc[j].x += v0 > 0.f ? v0 : 0.f;
      acc[j].y += v1 > 0.f ? v1 : 0.f;
    }
  }
  int r0g = y0 + 2 * wid, r1g = r0g + 1;
  float* d0 = partials + ((size_t)a * NXY + r0g) * NXY;
  float* d1 = d0 + NXY;
  if (accum) {
#pragma unroll
    for (int j = 0; j < 16; ++j) { d0[lane + 64 * j] += acc[j].x; d1[lane + 64 * j] += acc[j].y; }
  } else {
#pragma unroll
    for (int j = 0; j < 16; ++j) { d0[lane + 64 * j] = acc[j].x; d1[lane + 64 * j] = acc[j].y; }
  }
}

// fold partials -> IEst; re-init median state
__global__ void fold_kernel(const float* __restrict__ partials, float* __restrict__ iest,
                            unsigned* __restrict__ st) {
  int i = blockIdx.x * 256 + threadIdx.x;
  float s = 0.f;
#pragma unroll
  for (int a = 0; a < NACC; ++a) s += partials[(size_t)a * NXY * NXY + i];
  iest[i] = s;
  if (i == 0) { st[0] = 0u; st[1] = 0u; st[2] = RANK1; st[3] = RANK2; }
}

// Back-projection row irFFT + ReLU -> Back[512][512] plane. grid = (64). Rows y0=256+8*B0.
__global__ __launch_bounds__(256) void pass3_back_kernel(const cf* __restrict__ in,
                                                         float* __restrict__ back,
                                                         const float* __restrict__ ksump) {
  __shared__ cf B[4096];
  int tid = threadIdx.x, wid = tid >> 6, lane = tid & 63;
  cf* L = B + wid * 1024;
  int B0 = blockIdx.x;
  int y0 = LO_ + 8 * B0;
  float scale = 1.0f / (1048576.0f * ksump[0]);
#pragma unroll
  for (int h = 0; h < 2; ++h) {
    int kx = tid + 256 * h;
    const float4* src = (const float4*)(in + (size_t)kx * NXY + y0);
    float4 g0 = src[0], g1 = src[1], g2 = src[2], g3 = src[3];
    B[0 * 512 + kx] = make_float2(g0.x, g0.y);
    B[1 * 512 + kx] = make_float2(g0.z, g0.w);
    B[2 * 512 + kx] = make_float2(g1.x, g1.y);
    B[3 * 512 + kx] = make_float2(g1.z, g1.w);
    B[4 * 512 + kx] = make_float2(g2.x, g2.y);
    B[5 * 512 + kx] = make_float2(g2.z, g2.w);
    B[6 * 512 + kx] = make_float2(g3.x, g3.y);
    B[7 * 512 + kx] = make_float2(g3.z, g3.w);
  }
  __syncthreads();
  cf u0[8], u1[8];
#pragma unroll
  for (int j = 0; j < 8; ++j) {
    int k = lane + 64 * j;
    u0[j] = L[k];
    u1[j] = L[512 + k];
  }
#pragma unroll
  for (int j = 0; j < 8; ++j) {
    int k = lane + 64 * j;
    if (k == 0) {
      L[LSWZ(0)]   = make_float2(u0[j].x, u1[j].x);
      L[LSWZ(512)] = make_float2(u0[j].y, u1[j].y);
    } else {
      L[LSWZ(k)]        = make_float2(u0[j].x - u1[j].y, u0[j].y + u1[j].x);
      L[LSWZ(1024 - k)] = make_float2(u0[j].x + u1[j].y, u1[j].x - u0[j].y);
    }
  }
  cf r[16];
#pragma unroll
  for (int m = 0; m < 16; ++m) r[m] = L[LSWZ(lane + 64 * m)];
  fft1024_wave<1>(r, L, lane);
  int rp0 = 8 * B0 + 2 * wid, rp1 = rp0 + 1;  // ROI rows
#pragma unroll
  for (int j = 4; j < 12; ++j) {
    int c = lane + 64 * j - 256;
    float v0 = r[j].x * scale, v1 = r[j].y * scale;
    back[(size_t)rp0 * 512 + c] = v0 > 0.f ? v0 : 0.f;
    back[(size_t)rp1 * 512 + c] = v1 > 0.f ? v1 : 0.f;
  }
}

// obj *= Back (broadcast over z). float4 streaming, full grid. grid = 6144.
__global__ void mult_kernel(float* __restrict__ obj, const float* __restrict__ back) {
  int i = blockIdx.x * 256 + threadIdx.x;       // < 24*512*512/4 = 1572864
  int rc4 = i & 65535;                          // plane-local float4 index
  float4 b = ((const float4*)back)[rc4];
  float4 o = ((float4*)obj)[i];
  o.x *= b.x; o.y *= b.y; o.z *= b.z; o.w *= b.w;
  ((float4*)obj)[i] = o;
}

// ---------------- median (exact, 3-round radix-select; pick fused via last-block) ----------------
__global__ void medhist_kernel(const float* __restrict__ v, unsigned* __restrict__ st,
                               unsigned* __restrict__ hist, int shift, unsigned maskHigh, int nb,
                               int finalRound, float* __restrict__ tos) {
  extern __shared__ unsigned h[];
  __shared__ unsigned ps[256];
  __shared__ int lastFlag;
  int tid = threadIdx.x;
  for (int k = tid; k < 2 * nb; k += 256) h[k] = 0u;
  __syncthreads();
  unsigned p1 = st[0], p2 = st[1];
  unsigned bm = (unsigned)(nb - 1);
  for (int i = blockIdx.x * 256 + tid; i < NXY * NXY; i += gridDim.x * 256) {
    unsigned u = __float_as_uint(v[i]);
    unsigned b = (u >> shift) & bm;
    if ((u & maskHigh) == (p1 & maskHigh)) atomicAdd(&h[b], 1u);
    if ((u & maskHigh) == (p2 & maskHigh)) atomicAdd(&h[nb + b], 1u);
  }
  __syncthreads();
  for (int k = tid; k < 2 * nb; k += 256) atomicAdd(&hist[k], h[k]);
  __syncthreads();
  if (tid == 0) {
    __threadfence();
    lastFlag = (atomicAdd(&hist[4096], 1u) == (unsigned)(gridDim.x - 1)) ? 1 : 0;
  }
  __syncthreads();
  if (!lastFlag) return;
  int per = nb >> 8;
  for (int which = 0; which < 2; ++which) {
    unsigned loc[8];
    unsigned my = 0;
    for (int i = 0; i < per; ++i) { loc[i] = atomicAdd(&hist[which * nb + tid * per + i], 0u); my += loc[i]; }
    ps[tid] = my;
    __syncthreads();
    for (int off = 1; off < 256; off <<= 1) {
      unsigned vv = (tid >= off) ? ps[tid - off] : 0u;
      __syncthreads();
      ps[tid] += vv;
      __syncthreads();
    }
    unsigned pre = ps[tid] - my;
    unsigned rr = st[2 + which];
    if (rr >= pre && rr < pre + my) {
      unsigned cum = pre;
      for (int i = 0; i < per; ++i) {
        if (rr < cum + loc[i]) {
          st[which] |= (unsigned)(tid * per + i) << shift;
          st[2 + which] = rr - cum;
          break;
        }
        cum += loc[i];
      }
    }
    __syncthreads();
  }
  if (finalRound && tid == 0) {
    float m = 0.5f * (__uint_as_float(st[0]) + __uint_as_float(st[1]));
    tos[0] = m / SNR_;
  }
}

// ---------------- orchestration ----------------
extern "C" void kernel_launch(void* const* d_in, const int* in_sizes, int n_in,
                              void* d_out, int out_size, void* d_ws, size_t ws_size,
                              hipStream_t stream) {
  const float* imstack  = (const float*)d_in[0];
  const float* init_vol = (const float*)d_in[1];
  const float* conv_re  = (const float*)d_in[2];
  const float* conv_im  = (const float*)d_in[3];
  float* obj = (float*)d_out;

  char* w = (char*)d_ws;
  size_t off = 0;
  auto alloc = [&](size_t bytes) -> void* {
    void* p = (void*)(w + off);
    off += (bytes + 255) & ~(size_t)255;
    return p;
  };

  const size_t PLANE = (size_t)NXY * NXY;
  cf* KT         = (cf*)alloc((size_t)513 * NXY * sizeof(cf)); // 4.2 MB
  float* IExp    = (float*)alloc(PLANE * 4);
  float* IEst    = (float*)alloc(PLANE * 4);
  float* Partial = (float*)alloc((size_t)NACC * PLANE * 4);    // 16 MB
  float* Back    = (float*)alloc((size_t)512 * 512 * 4);       // 1 MB
  float* Ksum    = (float*)alloc(256);
  unsigned* St   = (unsigned*)alloc(256);
  unsigned* Hist = (unsigned*)alloc(3 * 4160 * 4);
  size_t fixedEnd = off;

  int ZC = 2;
  const int zcs[7] = {24, 12, 8, 6, 4, 3, 2};
  for (int i = 0; i < 7; ++i) {
    size_t need = fixedEnd + (size_t)zcs[i] * (S1 + S2) * sizeof(cf) + 4096;
    if (need <= ws_size) { ZC = zcs[i]; break; }
  }
  cf* bufC = (cf*)alloc((size_t)ZC * S1 * sizeof(cf));         // KXR (fwd) / KXY_b (back, needs >= 4MB)
  cf* bufD = (cf*)alloc((size_t)ZC * S2 * sizeof(cf));         // KXY
  float* Tos = Ksum + 1;

  hipMemcpyAsync(obj, init_vol, (size_t)NZ * ROI2 * ROI2 * 4, hipMemcpyDeviceToDevice, stream);
  hipMemsetAsync(Ksum, 0, 8, stream);
  ksum_kernel<<<256, 256, 0, stream>>>(conv_re, Ksum);
  imgexp_kernel<<<4096, 256, 0, stream>>>(imstack, IExp);
  buildkh_kernel<<<2052, 256, 0, stream>>>(conv_re, conv_im, KT);

  const int shifts[3] = {21, 10, 0};
  const int nbs[3]    = {2048, 2048, 1024};
  const unsigned masks[3] = {0u, 0xFFE00000u, 0xFFFFFC00u};

  for (int it = 0; it < ITN; ++it) {
    // forward projection in z-chunks
    for (int z0 = 0; z0 < NZ; z0 += ZC) {
      int zn = (NZ - z0 < ZC) ? (NZ - z0) : ZC;
      pass1_kernel<<<dim3(64, zn), 256, 0, stream>>>(obj + (size_t)z0 * ROI2 * ROI2, bufC);
      pass2_kernel<1><<<dim3(128, zn), 256, 0, stream>>>(bufC, KT, bufD, 0);
      pass3_fwd_kernel<<<dim3(128, NACC), 256, 0, stream>>>(bufD, Partial, Ksum, zn, z0 > 0 ? 1 : 0);
    }
    fold_kernel<<<4096, 256, 0, stream>>>(Partial, IEst, St);
    // exact median of IEst
    hipMemsetAsync(Hist, 0, 3 * 4160 * 4, stream);
    for (int round = 0; round < 3; ++round) {
      medhist_kernel<<<256, 256, 2 * nbs[round] * 4, stream>>>(IEst, St, Hist + round * 4160,
                                                               shifts[round], masks[round], nbs[round],
                                                               round == 2 ? 1 : 0, Tos);
    }
    // back projection
    pass1b_kernel<<<128, 256, 0, stream>>>(IExp, IEst, Tos, bufC);        // [kx 512][y 1024]
    pass2_kernel<0><<<dim3(128, 1), 256, 0, stream>>>(bufC, KT, bufD, 1); // [kx 512][y 1024]
    pass3_back_kernel<<<64, 256, 0, stream>>>(bufD, Back, Ksum);          // Back[512][512]
    mult_kernel<<<6144, 256, 0, stream>>>(obj, Back);
  }
}